// Round 1
// baseline (821.071 us; speedup 1.0000x reference)
//
#include <hip/hip_runtime.h>
#include <math.h>

// Problem constants: B=16, T=4096, D=512, N=9, K=1024, d=8
#define ROWS   65536

// ---- workspace float offsets (total ~699 KB) ----
#define WS_WPAD 0          // W_in_all padded [512][96]: col cc=8i+c at (cc/9)*12+cc%9
#define WS_WOUT 49152      // W_out_all [72][512], row jr = 8j+a
#define WS_CBT  86016      // normalized codebooks transposed [9][8][1024]
#define WS_SC   159744     // sum(cb_n^2) [9][1024]
#define WS_M    168960     // M[j][i][a*8+b] = sum_t Wout[j][a][t]*Win[i][t][b]
#define WS_CACC 174144     // [9][8]: sum_{j<i} out_b_j @ W_in_i
#define WS_SOB  174216     // [512]: sum_j out_b_j
#define WS_LOSS 174728     // double accumulator (8B aligned)

// ---- output float offsets ----
#define OUT_CODES 33554432
#define OUT_LAT   34144256
#define OUT_CLOSS 38862848
#define OUT_CBLOSS 38862849

__device__ __forceinline__ int pcol(int cc){ return (cc/9)*12 + (cc%9); }

// ---------------- prep1: weight-norm + codebook normalize ----------------
__global__ __launch_bounds__(256) void prep1(const float* __restrict__ in_v,
    const float* __restrict__ in_g, const float* __restrict__ out_v,
    const float* __restrict__ out_g, const float* __restrict__ out_b,
    const float* __restrict__ cb, float* __restrict__ ws)
{
    int t = blockIdx.x*256 + threadIdx.x;
    if (t < 9216) {
        // codebook normalize: (i,k)
        int i = t >> 10, k = t & 1023;
        const float* p = cb + (i*1024 + k)*8;
        float v[8]; float ssq = 0.f;
        #pragma unroll
        for (int c=0;c<8;c++){ v[c]=p[c]; ssq = fmaf(v[c],v[c],ssq); }
        float den = fmaxf(sqrtf(ssq), 1e-12f);
        float sc = 0.f;
        #pragma unroll
        for (int c=0;c<8;c++){ float cn = v[c]/den; ws[WS_CBT + (i*8+c)*1024 + k] = cn; sc = fmaf(cn,cn,sc); }
        ws[WS_SC + i*1024 + k] = sc;
    } else if (t < 13824) {
        // W_out: (j, t) norm over a-axis
        int r = t - 9216; int j = r >> 9, tt = r & 511;
        float v[8]; float ssq = 0.f;
        #pragma unroll
        for (int a=0;a<8;a++){ v[a]=out_v[(j*8+a)*512+tt]; ssq=fmaf(v[a],v[a],ssq); }
        float den = fmaxf(sqrtf(ssq), 1e-12f);
        float g = out_g[j*512+tt];
        #pragma unroll
        for (int a=0;a<8;a++) ws[WS_WOUT + (j*8+a)*512 + tt] = g*v[a]/den;
    } else if (t < 18432) {
        // W_in: one wave per (i,c) column, norm over 512 rows (range 64-aligned: 13824%256==0)
        int r = t - 13824;
        int w = r >> 6, l = r & 63;
        int i = w >> 3, c = w & 7;
        float v[8]; float ssq = 0.f;
        #pragma unroll
        for (int u=0;u<8;u++){ v[u] = in_v[(i*512 + l*8+u)*8 + c]; ssq = fmaf(v[u],v[u],ssq); }
        #pragma unroll
        for (int off=1; off<64; off<<=1) ssq += __shfl_xor(ssq, off, 64);
        float den = fmaxf(sqrtf(ssq), 1e-12f);
        float g = in_g[i*8+c];
        int pc = pcol(i*8+c);
        #pragma unroll
        for (int u=0;u<8;u++) ws[WS_WPAD + (l*8+u)*96 + pc] = g*v[u]/den;
    } else if (t < 18944) {
        int tt = t - 18432;
        float s = 0.f;
        for (int j=0;j<9;j++) s += out_b[j*512+tt];
        ws[WS_SOB + tt] = s;
    } else if (t == 18944) {
        *(double*)&ws[WS_LOSS] = 0.0;
    }
}

// ---------------- prep2: cross-term tables M and Cacc ----------------
__global__ __launch_bounds__(256) void prep2(const float* __restrict__ out_b,
                                             float* __restrict__ ws)
{
    int t = blockIdx.x*256 + threadIdx.x;
    if (t < 5184) {
        int j = t / 576; int rem = t % 576; int i = rem >> 6; int ab = rem & 63;
        int a = ab >> 3, b = ab & 7;
        int pc = pcol(i*8+b);
        const float* wo = ws + WS_WOUT + (j*8+a)*512;
        const float* wp = ws + WS_WPAD;
        float s = 0.f;
        for (int tt=0; tt<512; tt++) s = fmaf(wo[tt], wp[tt*96+pc], s);
        ws[WS_M + (j*9+i)*64 + ab] = s;
    } else if (t < 5256) {
        int r = t - 5184; int i = r >> 3, b = r & 7;
        int pc = pcol(i*8+b);
        float s = 0.f;
        for (int tt=0; tt<512; tt++) {
            float bb = 0.f;
            for (int j=0;j<i;j++) bb += out_b[j*512+tt];
            s = fmaf(bb, ws[WS_WPAD + tt*96+pc], s);
        }
        ws[WS_CACC + i*8 + b] = s;
    }
}

// ---------------- gemm_in: P = z @ W_in_all + in_b  -> latents region ----------------
__global__ __launch_bounds__(256) void gemm_in(const float* __restrict__ z,
    const float* __restrict__ in_b, const float* __restrict__ ws, float* __restrict__ out)
{
    __shared__ float AsT[32*132];   // [k][row], pad 132 keeps b128 aligned (528B = 33*16)
    __shared__ float Bs[32*96];     // [k][padded col groups of 12]
    int tid = threadIdx.x;
    int rowbase = blockIdx.x * 128;
    int tr = tid & 31, tc = tid >> 5;   // thread: rows tr*4..+3, cols tc*9..+8
    float acc[4][9];
    #pragma unroll
    for (int r=0;r<4;r++){
        #pragma unroll
        for(int c=0;c<9;c++) acc[r][c]=0.f;
    }
    int kq = tid & 7, rr = tid >> 3;
    for (int kk=0; kk<16; kk++) {
        #pragma unroll
        for (int p=0;p<4;p++){
            int row = rr + p*32;
            float4 a = *(const float4*)(z + (size_t)(rowbase+row)*512 + kk*32 + kq*4);
            AsT[(kq*4+0)*132 + row] = a.x;
            AsT[(kq*4+1)*132 + row] = a.y;
            AsT[(kq*4+2)*132 + row] = a.z;
            AsT[(kq*4+3)*132 + row] = a.w;
        }
        #pragma unroll
        for (int p=0;p<3;p++){
            int idx = p*256 + tid;
            *(float4*)(Bs + idx*4) = *(const float4*)(ws + WS_WPAD + kk*32*96 + idx*4);
        }
        __syncthreads();
        #pragma unroll 4
        for (int k=0;k<32;k++){
            float4 a  = *(const float4*)(AsT + k*132 + tr*4);
            float4 b0 = *(const float4*)(Bs + k*96 + tc*12);
            float4 b1 = *(const float4*)(Bs + k*96 + tc*12 + 4);
            float  b8 = Bs[k*96 + tc*12 + 8];
            float av[4] = {a.x,a.y,a.z,a.w};
            float bv[9] = {b0.x,b0.y,b0.z,b0.w,b1.x,b1.y,b1.z,b1.w,b8};
            #pragma unroll
            for (int r=0;r<4;r++){
                #pragma unroll
                for (int c=0;c<9;c++) acc[r][c] = fmaf(av[r], bv[c], acc[r][c]);
            }
        }
        __syncthreads();
    }
    #pragma unroll
    for (int c=0;c<9;c++){
        int cc = tc*9+c;
        float bias = in_b[cc];
        #pragma unroll
        for (int r=0;r<4;r++){
            int row = rowbase + tr*4 + r;
            out[OUT_LAT + (size_t)row*72 + cc] = acc[r][c] + bias;
        }
    }
}

// ---------------- step: one quantizer stage (launched 9x) ----------------
// thread = (row, k-quarter); 4 lanes per row; cb_n staged in LDS with quarter stagger.
__global__ __launch_bounds__(256) void step_kernel(int i,
    const float* __restrict__ cbooks, float* __restrict__ ws, float* __restrict__ out)
{
    __shared__ float lds_cb[8*1040];   // [c][q][260]: stagger 260 -> disjoint banks per quarter
    __shared__ float lds_sc[4*260];
    __shared__ float warr[4];
    int tid = threadIdx.x;
    #pragma unroll
    for (int p=0;p<8;p++){
        int s = (p*256 + tid)*4;
        int c = s >> 10; int r = s & 1023; int qq = r >> 8; int kk = r & 255;
        float4 v = *(const float4*)(ws + WS_CBT + i*8192 + s);
        *(float4*)(lds_cb + c*1040 + qq*260 + kk) = v;
    }
    {
        int s = tid*4;
        int qq = s >> 8; int kk = s & 255;
        float4 v = *(const float4*)(ws + WS_SC + i*1024 + s);
        *(float4*)(lds_sc + qq*260 + kk) = v;
    }
    __syncthreads();

    int gid = blockIdx.x*256 + tid;
    int row = gid >> 2;
    int q = tid & 3;

    // z_e = P_i - Cacc_i - sum_{j<i} q_j . M[j][i]
    float* lat = out + OUT_LAT + (size_t)row*72 + i*8;
    float4 p0 = *(const float4*)(lat);
    float4 p1 = *(const float4*)(lat+4);
    float ze[8] = {p0.x,p0.y,p0.z,p0.w,p1.x,p1.y,p1.z,p1.w};
    #pragma unroll
    for (int b=0;b<8;b++) ze[b] -= ws[WS_CACC + i*8 + b];
    for (int j=0;j<i;j++){
        int kj = (int)out[OUT_CODES + (size_t)row*9 + j];
        const float* qp = cbooks + (j*1024+kj)*8;
        float4 q0 = *(const float4*)(qp);
        float4 q1 = *(const float4*)(qp+4);
        float qa[8] = {q0.x,q0.y,q0.z,q0.w,q1.x,q1.y,q1.z,q1.w};
        const float* M = ws + WS_M + (j*9+i)*64;
        #pragma unroll
        for (int a=0;a<8;a++){
            #pragma unroll
            for (int b=0;b<8;b++) ze[b] = fmaf(-qa[a], M[a*8+b], ze[b]);
        }
    }
    // l2-normalize (match ref: x / max(||x||, 1e-12))
    float ssq = 0.f;
    #pragma unroll
    for (int c=0;c<8;c++) ssq = fmaf(ze[c],ze[c],ssq);
    float den = fmaxf(sqrtf(ssq), 1e-12f);
    float zen[8];
    #pragma unroll
    for (int c=0;c<8;c++) zen[c] = ze[c]/den;
    float se = 0.f;
    #pragma unroll
    for (int c=0;c<8;c++) se = fmaf(zen[c],zen[c],se);

    // dist = se - 2*dot + s_c, argmin with first-occurrence tie-break
    const float* cbq = lds_cb + q*260;
    const float* scq = lds_sc + q*260;
    float bestd = 1e30f; int bestk = 0;
    const int kbase = q*256;
    #pragma unroll 2
    for (int kk=0; kk<256; kk+=4){
        float d0=0.f,d1=0.f,d2=0.f,d3=0.f;
        #pragma unroll
        for (int c=0;c<8;c++){
            float4 v = *(const float4*)(cbq + c*1040 + kk);
            d0 = fmaf(zen[c], v.x, d0);
            d1 = fmaf(zen[c], v.y, d1);
            d2 = fmaf(zen[c], v.z, d2);
            d3 = fmaf(zen[c], v.w, d3);
        }
        float4 sc4 = *(const float4*)(scq + kk);
        float t0 = fmaf(d0,-2.0f,se)+sc4.x;
        float t1 = fmaf(d1,-2.0f,se)+sc4.y;
        float t2 = fmaf(d2,-2.0f,se)+sc4.z;
        float t3 = fmaf(d3,-2.0f,se)+sc4.w;
        bool c0 = t0<bestd; bestk = c0?(kbase+kk+0):bestk; bestd = c0?t0:bestd;
        bool c1 = t1<bestd; bestk = c1?(kbase+kk+1):bestk; bestd = c1?t1:bestd;
        bool c2 = t2<bestd; bestk = c2?(kbase+kk+2):bestk; bestd = c2?t2:bestd;
        bool c3 = t3<bestd; bestk = c3?(kbase+kk+3):bestk; bestd = c3?t3:bestd;
    }
    // combine 4 quarters (lanes l^1, l^2 share the row); equal dist -> smaller k
    #pragma unroll
    for (int off=1; off<4; off<<=1){
        float od = __shfl_xor(bestd, off, 64);
        int   ok = __shfl_xor(bestk, off, 64);
        if (od < bestd || (od == bestd && ok < bestk)) { bestd = od; bestk = ok; }
    }

    float lpart = 0.f;
    if (q == 0){
        out[OUT_CODES + (size_t)row*9 + i] = (float)bestk;
        float4 z0 = {ze[0],ze[1],ze[2],ze[3]};
        float4 z1 = {ze[4],ze[5],ze[6],ze[7]};
        *(float4*)(lat)   = z0;
        *(float4*)(lat+4) = z1;
        const float* qp = cbooks + (i*1024+bestk)*8;
        #pragma unroll
        for (int c=0;c<8;c++){ float dd = ze[c]-qp[c]; lpart = fmaf(dd,dd,lpart); }
    }
    #pragma unroll
    for (int off=1; off<64; off<<=1) lpart += __shfl_xor(lpart, off, 64);
    if ((tid & 63)==0) warr[tid>>6] = lpart;
    __syncthreads();
    if (tid==0){
        double bs = (double)warr[0]+(double)warr[1]+(double)warr[2]+(double)warr[3];
        atomicAdd((double*)&ws[WS_LOSS], bs);
    }
}

// ---------------- gemm_out: z_q = Q @ W_out_all + sum_out_b ----------------
__global__ __launch_bounds__(256) void gemm_out(const float* __restrict__ cbooks,
    const float* __restrict__ ws, float* __restrict__ out)
{
    __shared__ float QL[64*76];
    __shared__ float Ws[72*128];
    int tid = threadIdx.x;
    int rowbase = blockIdx.x*64;
    if (tid < 64){
        int row = rowbase + tid;
        for (int j=0;j<9;j++){
            int kj = (int)out[OUT_CODES + (size_t)row*9 + j];
            const float* qp = cbooks + (j*1024+kj)*8;
            float4 q0 = *(const float4*)qp;
            float4 q1 = *(const float4*)(qp+4);
            *(float4*)(QL + tid*76 + j*8)     = q0;
            *(float4*)(QL + tid*76 + j*8 + 4) = q1;
        }
    }
    int tr = tid & 15, tc = tid >> 4;   // rows tr*4..+3, cols tc*8..+7 within 128-chunk
    for (int cc=0; cc<4; cc++){
        __syncthreads();
        #pragma unroll
        for (int p=0;p<9;p++){
            int idx = p*256 + tid;
            int jr = idx >> 5; int cq = idx & 31;
            *(float4*)(Ws + jr*128 + cq*4) = *(const float4*)(ws + WS_WOUT + jr*512 + cc*128 + cq*4);
        }
        __syncthreads();
        float acc[4][8];
        #pragma unroll
        for (int r=0;r<4;r++){
            #pragma unroll
            for (int c=0;c<8;c++) acc[r][c]=0.f;
        }
        #pragma unroll 4
        for (int k=0;k<72;k++){
            float a0 = QL[(tr*4+0)*76 + k];
            float a1 = QL[(tr*4+1)*76 + k];
            float a2 = QL[(tr*4+2)*76 + k];
            float a3 = QL[(tr*4+3)*76 + k];
            float4 b0 = *(const float4*)(Ws + k*128 + tc*8);
            float4 b1 = *(const float4*)(Ws + k*128 + tc*8 + 4);
            float bv[8] = {b0.x,b0.y,b0.z,b0.w,b1.x,b1.y,b1.z,b1.w};
            float av[4] = {a0,a1,a2,a3};
            #pragma unroll
            for (int r=0;r<4;r++){
                #pragma unroll
                for (int c=0;c<8;c++) acc[r][c] = fmaf(av[r], bv[c], acc[r][c]);
            }
        }
        float4 s0 = *(const float4*)(ws + WS_SOB + cc*128 + tc*8);
        float4 s1 = *(const float4*)(ws + WS_SOB + cc*128 + tc*8 + 4);
        #pragma unroll
        for (int r=0;r<4;r++){
            int row = rowbase + tr*4 + r;
            float4 o0 = {acc[r][0]+s0.x, acc[r][1]+s0.y, acc[r][2]+s0.z, acc[r][3]+s0.w};
            float4 o1 = {acc[r][4]+s1.x, acc[r][5]+s1.y, acc[r][6]+s1.z, acc[r][7]+s1.w};
            *(float4*)(out + (size_t)row*512 + cc*128 + tc*8)     = o0;
            *(float4*)(out + (size_t)row*512 + cc*128 + tc*8 + 4) = o1;
        }
    }
    if (blockIdx.x==0 && tid==0){
        double L = *(const double*)(ws + WS_LOSS);
        float lv = (float)(L * (1.0/524288.0));   // / (B*T*d)
        out[OUT_CLOSS]  = lv;
        out[OUT_CBLOSS] = lv;
    }
}

extern "C" void kernel_launch(void* const* d_in, const int* in_sizes, int n_in,
                              void* d_out, int out_size, void* d_ws, size_t ws_size,
                              hipStream_t stream) {
    const float* z     = (const float*)d_in[0];
    const float* in_v  = (const float*)d_in[1];
    const float* in_g  = (const float*)d_in[2];
    const float* in_b  = (const float*)d_in[3];
    const float* out_v = (const float*)d_in[4];
    const float* out_g = (const float*)d_in[5];
    const float* out_b = (const float*)d_in[6];
    const float* cb    = (const float*)d_in[7];
    float* out = (float*)d_out;
    float* ws  = (float*)d_ws;

    prep1<<<75, 256, 0, stream>>>(in_v, in_g, out_v, out_g, out_b, cb, ws);
    prep2<<<21, 256, 0, stream>>>(out_b, ws);
    gemm_in<<<512, 256, 0, stream>>>(z, in_b, ws, out);
    for (int i=0; i<9; i++)
        step_kernel<<<1024, 256, 0, stream>>>(i, cb, ws, out);
    gemm_out<<<1024, 256, 0, stream>>>(cb, ws, out);
}

// Round 2
// 672.655 us; speedup vs baseline: 1.2206x; 1.2206x over previous
//
#include <hip/hip_runtime.h>
#include <math.h>

// Problem constants: B=16, T=4096, D=512, N=9, K=1024, d=8
#define ROWS   65536

// ---- workspace float offsets (total ~699 KB) ----
#define WS_WPAD 0          // W_in_all padded [512][96]: col cc=8i+c at (cc/9)*12+cc%9
#define WS_WOUT 49152      // W_out_all [72][512], row jr = 8j+a
#define WS_CBT  86016      // normalized codebooks transposed [9][8][1024]
#define WS_SC   159744     // sum(cb_n^2) [9][1024]
#define WS_M    168960     // M[j][i][a*8+b] = sum_t Wout[j][a][t]*Win[i][t][b]
#define WS_CACC 174144     // [9][8]: sum_{j<i} out_b_j @ W_in_i
#define WS_SOB  174216     // [512]: sum_j out_b_j
#define WS_LOSS 174728     // double accumulator (8B aligned)

// ---- output float offsets ----
#define OUT_CODES 33554432
#define OUT_LAT   34144256
#define OUT_CLOSS 38862848
#define OUT_CBLOSS 38862849

__device__ __forceinline__ int pcol(int cc){ return (cc/9)*12 + (cc%9); }

// ---------------- prep1: weight-norm + codebook normalize ----------------
__global__ __launch_bounds__(256) void prep1(const float* __restrict__ in_v,
    const float* __restrict__ in_g, const float* __restrict__ out_v,
    const float* __restrict__ out_g, const float* __restrict__ out_b,
    const float* __restrict__ cb, float* __restrict__ ws)
{
    int t = blockIdx.x*256 + threadIdx.x;
    if (t < 9216) {
        // codebook normalize: (i,k)
        int i = t >> 10, k = t & 1023;
        const float* p = cb + (i*1024 + k)*8;
        float v[8]; float ssq = 0.f;
        #pragma unroll
        for (int c=0;c<8;c++){ v[c]=p[c]; ssq = fmaf(v[c],v[c],ssq); }
        float den = fmaxf(sqrtf(ssq), 1e-12f);
        float sc = 0.f;
        #pragma unroll
        for (int c=0;c<8;c++){ float cn = v[c]/den; ws[WS_CBT + (i*8+c)*1024 + k] = cn; sc = fmaf(cn,cn,sc); }
        ws[WS_SC + i*1024 + k] = sc;
    } else if (t < 13824) {
        // W_out: (j, t) norm over a-axis
        int r = t - 9216; int j = r >> 9, tt = r & 511;
        float v[8]; float ssq = 0.f;
        #pragma unroll
        for (int a=0;a<8;a++){ v[a]=out_v[(j*8+a)*512+tt]; ssq=fmaf(v[a],v[a],ssq); }
        float den = fmaxf(sqrtf(ssq), 1e-12f);
        float g = out_g[j*512+tt];
        #pragma unroll
        for (int a=0;a<8;a++) ws[WS_WOUT + (j*8+a)*512 + tt] = g*v[a]/den;
    } else if (t < 18432) {
        // W_in: one wave per (i,c) column, norm over 512 rows (range 64-aligned: 13824%256==0)
        int r = t - 13824;
        int w = r >> 6, l = r & 63;
        int i = w >> 3, c = w & 7;
        float v[8]; float ssq = 0.f;
        #pragma unroll
        for (int u=0;u<8;u++){ v[u] = in_v[(i*512 + l*8+u)*8 + c]; ssq = fmaf(v[u],v[u],ssq); }
        #pragma unroll
        for (int off=1; off<64; off<<=1) ssq += __shfl_xor(ssq, off, 64);
        float den = fmaxf(sqrtf(ssq), 1e-12f);
        float g = in_g[i*8+c];
        int pc = pcol(i*8+c);
        #pragma unroll
        for (int u=0;u<8;u++) ws[WS_WPAD + (l*8+u)*96 + pc] = g*v[u]/den;
    } else if (t < 18944) {
        int tt = t - 18432;
        float s = 0.f;
        for (int j=0;j<9;j++) s += out_b[j*512+tt];
        ws[WS_SOB + tt] = s;
    } else if (t == 18944) {
        *(double*)&ws[WS_LOSS] = 0.0;
    }
}

// ---------------- prep2: cross-term tables M and Cacc (8 lanes per output) ----
// M: 5184 outputs x 8 partials = 41472 threads (blocks 0..161)
// Cacc: 72 outputs x 8 partials = 576 threads (blocks 162..164)
__global__ __launch_bounds__(256) void prep2(const float* __restrict__ out_b,
                                             float* __restrict__ ws)
{
    int g = blockIdx.x*256 + threadIdx.x;
    if (g < 41472) {
        int oi = g >> 3, part = g & 7;
        int j = oi / 576; int rem = oi % 576; int i = rem >> 6; int ab = rem & 63;
        int a = ab >> 3, b = ab & 7;
        int pc = pcol(i*8+b);
        const float* wo = ws + WS_WOUT + (j*8+a)*512 + part*64;
        const float* wp = ws + WS_WPAD + (part*64)*96 + pc;
        float s = 0.f;
        #pragma unroll
        for (int u=0; u<16; u++) {
            float4 w4 = *(const float4*)(wo + u*4);
            s = fmaf(w4.x, wp[(u*4+0)*96], s);
            s = fmaf(w4.y, wp[(u*4+1)*96], s);
            s = fmaf(w4.z, wp[(u*4+2)*96], s);
            s = fmaf(w4.w, wp[(u*4+3)*96], s);
        }
        // sum the 8 consecutive-lane partials (same output)
        #pragma unroll
        for (int off=1; off<8; off<<=1) s += __shfl_xor(s, off, 64);
        if (part == 0) ws[WS_M + oi] = s;   // oi == (j*9+i)*64 + ab
    } else if (g < 42048) {
        int r = g - 41472;
        int oi = r >> 3, part = r & 7;
        int i = oi >> 3, b = oi & 7;
        int pc = pcol(i*8+b);
        float s = 0.f;
        for (int u=0; u<64; u++) {
            int tt = part*64 + u;
            float bb = 0.f;
            for (int j=0;j<i;j++) bb += out_b[j*512+tt];
            s = fmaf(bb, ws[WS_WPAD + tt*96+pc], s);
        }
        #pragma unroll
        for (int off=1; off<8; off<<=1) s += __shfl_xor(s, off, 64);
        if (part == 0) ws[WS_CACC + oi] = s;
    }
}

// ---------------- gemm_in: P = z @ W_in_all + in_b  -> latents region ----------------
__global__ __launch_bounds__(256) void gemm_in(const float* __restrict__ z,
    const float* __restrict__ in_b, const float* __restrict__ ws, float* __restrict__ out)
{
    __shared__ float AsT[32*132];   // [k][row], pad 132 keeps b128 aligned (528B = 33*16)
    __shared__ float Bs[32*96];     // [k][padded col groups of 12]
    int tid = threadIdx.x;
    int rowbase = blockIdx.x * 128;
    int tr = tid & 31, tc = tid >> 5;   // thread: rows tr*4..+3, cols tc*9..+8
    float acc[4][9];
    #pragma unroll
    for (int r=0;r<4;r++){
        #pragma unroll
        for(int c=0;c<9;c++) acc[r][c]=0.f;
    }
    int kq = tid & 7, rr = tid >> 3;
    for (int kk=0; kk<16; kk++) {
        #pragma unroll
        for (int p=0;p<4;p++){
            int row = rr + p*32;
            float4 a = *(const float4*)(z + (size_t)(rowbase+row)*512 + kk*32 + kq*4);
            AsT[(kq*4+0)*132 + row] = a.x;
            AsT[(kq*4+1)*132 + row] = a.y;
            AsT[(kq*4+2)*132 + row] = a.z;
            AsT[(kq*4+3)*132 + row] = a.w;
        }
        #pragma unroll
        for (int p=0;p<3;p++){
            int idx = p*256 + tid;
            *(float4*)(Bs + idx*4) = *(const float4*)(ws + WS_WPAD + kk*32*96 + idx*4);
        }
        __syncthreads();
        #pragma unroll 4
        for (int k=0;k<32;k++){
            float4 a  = *(const float4*)(AsT + k*132 + tr*4);
            float4 b0 = *(const float4*)(Bs + k*96 + tc*12);
            float4 b1 = *(const float4*)(Bs + k*96 + tc*12 + 4);
            float  b8 = Bs[k*96 + tc*12 + 8];
            float av[4] = {a.x,a.y,a.z,a.w};
            float bv[9] = {b0.x,b0.y,b0.z,b0.w,b1.x,b1.y,b1.z,b1.w,b8};
            #pragma unroll
            for (int r=0;r<4;r++){
                #pragma unroll
                for (int c=0;c<9;c++) acc[r][c] = fmaf(av[r], bv[c], acc[r][c]);
            }
        }
        __syncthreads();
    }
    #pragma unroll
    for (int c=0;c<9;c++){
        int cc = tc*9+c;
        float bias = in_b[cc];
        #pragma unroll
        for (int r=0;r<4;r++){
            int row = rowbase + tr*4 + r;
            out[OUT_LAT + (size_t)row*72 + cc] = acc[r][c] + bias;
        }
    }
}

// ---------------- step: one quantizer stage (launched 9x) ----------------
// thread = (row, k-quarter); 4 lanes per row; cb_n staged in LDS with quarter stagger.
__global__ __launch_bounds__(256) void step_kernel(int i,
    const float* __restrict__ cbooks, float* __restrict__ ws, float* __restrict__ out)
{
    __shared__ float lds_cb[8*1040];   // [c][q][260]: stagger 260 -> disjoint banks per quarter
    __shared__ float lds_sc[4*260];
    __shared__ float warr[4];
    int tid = threadIdx.x;
    #pragma unroll
    for (int p=0;p<8;p++){
        int s = (p*256 + tid)*4;
        int c = s >> 10; int r = s & 1023; int qq = r >> 8; int kk = r & 255;
        float4 v = *(const float4*)(ws + WS_CBT + i*8192 + s);
        *(float4*)(lds_cb + c*1040 + qq*260 + kk) = v;
    }
    {
        int s = tid*4;
        int qq = s >> 8; int kk = s & 255;
        float4 v = *(const float4*)(ws + WS_SC + i*1024 + s);
        *(float4*)(lds_sc + qq*260 + kk) = v;
    }
    __syncthreads();

    int gid = blockIdx.x*256 + tid;
    int row = gid >> 2;
    int q = tid & 3;

    // z_e = P_i - Cacc_i - sum_{j<i} q_j . M[j][i]
    float* lat = out + OUT_LAT + (size_t)row*72 + i*8;
    float4 p0 = *(const float4*)(lat);
    float4 p1 = *(const float4*)(lat+4);
    float ze[8] = {p0.x,p0.y,p0.z,p0.w,p1.x,p1.y,p1.z,p1.w};
    #pragma unroll
    for (int b=0;b<8;b++) ze[b] -= ws[WS_CACC + i*8 + b];
    for (int j=0;j<i;j++){
        int kj = (int)out[OUT_CODES + (size_t)row*9 + j];
        const float* qp = cbooks + (j*1024+kj)*8;
        float4 q0 = *(const float4*)(qp);
        float4 q1 = *(const float4*)(qp+4);
        float qa[8] = {q0.x,q0.y,q0.z,q0.w,q1.x,q1.y,q1.z,q1.w};
        const float* M = ws + WS_M + (j*9+i)*64;
        #pragma unroll
        for (int a=0;a<8;a++){
            #pragma unroll
            for (int b=0;b<8;b++) ze[b] = fmaf(-qa[a], M[a*8+b], ze[b]);
        }
    }
    // l2-normalize (match ref: x / max(||x||, 1e-12))
    float ssq = 0.f;
    #pragma unroll
    for (int c=0;c<8;c++) ssq = fmaf(ze[c],ze[c],ssq);
    float den = fmaxf(sqrtf(ssq), 1e-12f);
    float zen[8];
    #pragma unroll
    for (int c=0;c<8;c++) zen[c] = ze[c]/den;
    float se = 0.f;
    #pragma unroll
    for (int c=0;c<8;c++) se = fmaf(zen[c],zen[c],se);

    // dist = se - 2*dot + s_c, argmin with first-occurrence tie-break
    const float* cbq = lds_cb + q*260;
    const float* scq = lds_sc + q*260;
    float bestd = 1e30f; int bestk = 0;
    const int kbase = q*256;
    #pragma unroll 2
    for (int kk=0; kk<256; kk+=4){
        float d0=0.f,d1=0.f,d2=0.f,d3=0.f;
        #pragma unroll
        for (int c=0;c<8;c++){
            float4 v = *(const float4*)(cbq + c*1040 + kk);
            d0 = fmaf(zen[c], v.x, d0);
            d1 = fmaf(zen[c], v.y, d1);
            d2 = fmaf(zen[c], v.z, d2);
            d3 = fmaf(zen[c], v.w, d3);
        }
        float4 sc4 = *(const float4*)(scq + kk);
        float t0 = fmaf(d0,-2.0f,se)+sc4.x;
        float t1 = fmaf(d1,-2.0f,se)+sc4.y;
        float t2 = fmaf(d2,-2.0f,se)+sc4.z;
        float t3 = fmaf(d3,-2.0f,se)+sc4.w;
        bool c0 = t0<bestd; bestk = c0?(kbase+kk+0):bestk; bestd = c0?t0:bestd;
        bool c1 = t1<bestd; bestk = c1?(kbase+kk+1):bestk; bestd = c1?t1:bestd;
        bool c2 = t2<bestd; bestk = c2?(kbase+kk+2):bestk; bestd = c2?t2:bestd;
        bool c3 = t3<bestd; bestk = c3?(kbase+kk+3):bestk; bestd = c3?t3:bestd;
    }
    // combine 4 quarters (lanes l^1, l^2 share the row); equal dist -> smaller k
    #pragma unroll
    for (int off=1; off<4; off<<=1){
        float od = __shfl_xor(bestd, off, 64);
        int   ok = __shfl_xor(bestk, off, 64);
        if (od < bestd || (od == bestd && ok < bestk)) { bestd = od; bestk = ok; }
    }

    float lpart = 0.f;
    if (q == 0){
        out[OUT_CODES + (size_t)row*9 + i] = (float)bestk;
        float4 z0 = {ze[0],ze[1],ze[2],ze[3]};
        float4 z1 = {ze[4],ze[5],ze[6],ze[7]};
        *(float4*)(lat)   = z0;
        *(float4*)(lat+4) = z1;
        const float* qp = cbooks + (i*1024+bestk)*8;
        #pragma unroll
        for (int c=0;c<8;c++){ float dd = ze[c]-qp[c]; lpart = fmaf(dd,dd,lpart); }
    }
    #pragma unroll
    for (int off=1; off<64; off<<=1) lpart += __shfl_xor(lpart, off, 64);
    if ((tid & 63)==0) warr[tid>>6] = lpart;
    __syncthreads();
    if (tid==0){
        double bs = (double)warr[0]+(double)warr[1]+(double)warr[2]+(double)warr[3];
        atomicAdd((double*)&ws[WS_LOSS], bs);
    }
}

// ---------------- gemm_out: z_q = Q @ W_out_all + sum_out_b ----------------
__global__ __launch_bounds__(256) void gemm_out(const float* __restrict__ cbooks,
    const float* __restrict__ ws, float* __restrict__ out)
{
    __shared__ float QL[64*76];
    __shared__ float Ws[72*128];
    int tid = threadIdx.x;
    int rowbase = blockIdx.x*64;
    if (tid < 64){
        int row = rowbase + tid;
        for (int j=0;j<9;j++){
            int kj = (int)out[OUT_CODES + (size_t)row*9 + j];
            const float* qp = cbooks + (j*1024+kj)*8;
            float4 q0 = *(const float4*)qp;
            float4 q1 = *(const float4*)(qp+4);
            *(float4*)(QL + tid*76 + j*8)     = q0;
            *(float4*)(QL + tid*76 + j*8 + 4) = q1;
        }
    }
    int tr = tid & 15, tc = tid >> 4;   // rows tr*4..+3, cols tc*8..+7 within 128-chunk
    for (int cc=0; cc<4; cc++){
        __syncthreads();
        #pragma unroll
        for (int p=0;p<9;p++){
            int idx = p*256 + tid;
            int jr = idx >> 5; int cq = idx & 31;
            *(float4*)(Ws + jr*128 + cq*4) = *(const float4*)(ws + WS_WOUT + jr*512 + cc*128 + cq*4);
        }
        __syncthreads();
        float acc[4][8];
        #pragma unroll
        for (int r=0;r<4;r++){
            #pragma unroll
            for (int c=0;c<8;c++) acc[r][c]=0.f;
        }
        #pragma unroll 4
        for (int k=0;k<72;k++){
            float a0 = QL[(tr*4+0)*76 + k];
            float a1 = QL[(tr*4+1)*76 + k];
            float a2 = QL[(tr*4+2)*76 + k];
            float a3 = QL[(tr*4+3)*76 + k];
            float4 b0 = *(const float4*)(Ws + k*128 + tc*8);
            float4 b1 = *(const float4*)(Ws + k*128 + tc*8 + 4);
            float bv[8] = {b0.x,b0.y,b0.z,b0.w,b1.x,b1.y,b1.z,b1.w};
            float av[4] = {a0,a1,a2,a3};
            #pragma unroll
            for (int r=0;r<4;r++){
                #pragma unroll
                for (int c=0;c<8;c++) acc[r][c] = fmaf(av[r], bv[c], acc[r][c]);
            }
        }
        float4 s0 = *(const float4*)(ws + WS_SOB + cc*128 + tc*8);
        float4 s1 = *(const float4*)(ws + WS_SOB + cc*128 + tc*8 + 4);
        #pragma unroll
        for (int r=0;r<4;r++){
            int row = rowbase + tr*4 + r;
            float4 o0 = {acc[r][0]+s0.x, acc[r][1]+s0.y, acc[r][2]+s0.z, acc[r][3]+s0.w};
            float4 o1 = {acc[r][4]+s1.x, acc[r][5]+s1.y, acc[r][6]+s1.z, acc[r][7]+s1.w};
            *(float4*)(out + (size_t)row*512 + cc*128 + tc*8)     = o0;
            *(float4*)(out + (size_t)row*512 + cc*128 + tc*8 + 4) = o1;
        }
    }
    if (blockIdx.x==0 && tid==0){
        double L = *(const double*)(ws + WS_LOSS);
        float lv = (float)(L * (1.0/524288.0));   // / (B*T*d)
        out[OUT_CLOSS]  = lv;
        out[OUT_CBLOSS] = lv;
    }
}

extern "C" void kernel_launch(void* const* d_in, const int* in_sizes, int n_in,
                              void* d_out, int out_size, void* d_ws, size_t ws_size,
                              hipStream_t stream) {
    const float* z     = (const float*)d_in[0];
    const float* in_v  = (const float*)d_in[1];
    const float* in_g  = (const float*)d_in[2];
    const float* in_b  = (const float*)d_in[3];
    const float* out_v = (const float*)d_in[4];
    const float* out_g = (const float*)d_in[5];
    const float* out_b = (const float*)d_in[6];
    const float* cb    = (const float*)d_in[7];
    float* out = (float*)d_out;
    float* ws  = (float*)d_ws;

    prep1<<<75, 256, 0, stream>>>(in_v, in_g, out_v, out_g, out_b, cb, ws);
    prep2<<<165, 256, 0, stream>>>(out_b, ws);
    gemm_in<<<512, 256, 0, stream>>>(z, in_b, ws, out);
    for (int i=0; i<9; i++)
        step_kernel<<<1024, 256, 0, stream>>>(i, cb, ws, out);
    gemm_out<<<1024, 256, 0, stream>>>(cb, ws, out);
}